// Round 1
// baseline (97.515 us; speedup 1.0000x reference)
//
#include <hip/hip_runtime.h>

#define NB 2048
#define NC 16
#define ND 256
#define THRED 0.8f
#define OUTW 353        // ND + 2*3*NC + 1
#define LSTR 260        // LDS row stride in floats (pad: 260%32=4 -> conflict-free)

// ---------------- Kernel 1: per-row L2 norms -> d_ws ----------------
__global__ __launch_bounds__(256) void norm_kernel(const float* __restrict__ e,
                                                   float* __restrict__ nrm) {
    int row  = blockIdx.x * 4 + (threadIdx.x >> 6);
    int lane = threadIdx.x & 63;
    float4 v = reinterpret_cast<const float4*>(e)[row * (ND / 4) + lane];
    float s = v.x * v.x + v.y * v.y + v.z * v.z + v.w * v.w;
#pragma unroll
    for (int off = 32; off; off >>= 1) s += __shfl_xor(s, off, 64);
    if (lane == 0) nrm[row] = sqrtf(s);
}

// ---------------- Kernel 2: one block per b ----------------
__global__ __launch_bounds__(256) void graph_kernel(const float* __restrict__ e,
                                                    const int* __restrict__ nm,
                                                    const float* __restrict__ nrm,
                                                    float* __restrict__ out) {
    const int b = blockIdx.x;
    const int t = threadIdx.x;
    const int i = t >> 4, j = t & 15;

    __shared__ float As[NC * LSTR];
    __shared__ float Bs[NC * LSTR];
    __shared__ float Msk[6][NC];

    // stage A = E_b (16 x 256 floats), coalesced float4
#pragma unroll
    for (int q = 0; q < 4; ++q) {
        int f = q * 1024 + t * 4;
        int r = f >> 8, c = f & 255;
        float4 v = *reinterpret_cast<const float4*>(e + (size_t)(b * NC + r) * ND + c);
        *reinterpret_cast<float4*>(&As[r * LSTR + c]) = v;
    }

    // cumulative 0/1 mask products, one per (part p, column jj)
    // p=0,1,2 : left k=1,2,3  -> prod_{u=1..k} nm[b-u, jj], 0 if b-k<0
    // p=3,4,5 : right k=1,2,3 -> prod_{u=0..k-1} nm[b+u, jj], 0 if b+k>=NB
    if (t < 96) {
        int p = t >> 4, jj = t & 15;
        int k = (p % 3) + 1;
        float m = 0.f;
        if (p < 3) {
            if (b - k >= 0) {
                m = 1.f;
                for (int u = 1; u <= k; ++u) m *= (float)nm[(b - u) * NC + jj];
            }
        } else {
            if (b + k < NB) {
                m = 1.f;
                for (int u = 0; u < k; ++u) m *= (float)nm[(b + u) * NC + jj];
            }
        }
        Msk[p][jj] = m;
    }

    const float na = nrm[b * NC + i];
    float neigh[NC];
#pragma unroll
    for (int r = 0; r < NC; ++r) neigh[r] = 0.f;
    float simv[6];

    const int offs[6] = {-1, -2, -3, 1, 2, 3};

    for (int p = 0; p < 6; ++p) {
        const int bb = b + offs[p];
        const bool inr = (bb >= 0) && (bb < NB);
        __syncthreads();   // readers of Bs (prev iter) done; also covers As/Msk staging at p==0
        if (inr) {
#pragma unroll
            for (int q = 0; q < 4; ++q) {
                int f = q * 1024 + t * 4;
                int r = f >> 8, c = f & 255;
                float4 v = *reinterpret_cast<const float4*>(e + (size_t)(bb * NC + r) * ND + c);
                *reinterpret_cast<float4*>(&Bs[r * LSTR + c]) = v;
            }
        } else {
#pragma unroll
            for (int q = 0; q < 4; ++q) {
                int f = q * 1024 + t * 4;
                int r = f >> 8, c = f & 255;
                *reinterpret_cast<float4*>(&Bs[r * LSTR + c]) = make_float4(0.f, 0.f, 0.f, 0.f);
            }
        }
        __syncthreads();

        // dot(e[b,i], e[bb,j]) over 256 dims via LDS
        float acc = 0.f;
#pragma unroll 8
        for (int d = 0; d < ND; d += 4) {
            float4 a  = *reinterpret_cast<const float4*>(&As[i * LSTR + d]);
            float4 bv = *reinterpret_cast<const float4*>(&Bs[j * LSTR + d]);
            acc = fmaf(a.x, bv.x, acc);
            acc = fmaf(a.y, bv.y, acc);
            acc = fmaf(a.z, bv.z, acc);
            acc = fmaf(a.w, bv.w, acc);
        }
        const float m  = Msk[p][j];
        const float nb = inr ? nrm[bb * NC + j] : 0.f;
        float sim = 0.f;
        if (m != 0.f) {
            sim = acc / fmaxf(na * nb, 1e-8f);
            sim = (sim > THRED) ? fminf(sim, 1.0f) : 0.f;
        }
        simv[p] = sim;

        // neighbor-embedding: this thread owns dim d = t for all 16 rows
#pragma unroll
        for (int r = 0; r < NC; ++r) {
            neigh[r] = fmaf(Msk[p][r], Bs[r * LSTR + t], neigh[r]);
        }
    }

    // L1 row sum of adj: sum sims over j (16-lane groups share i), +1 for ones col
    float part = simv[0] + simv[1] + simv[2] + simv[3] + simv[4] + simv[5];
#pragma unroll
    for (int o = 1; o < 16; o <<= 1) part += __shfl_xor(part, o, 64);
    const float inv = 1.0f / fmaxf(part + 1.0f, 1e-12f);

    float* orow = out + (size_t)(b * NC + i) * OUTW;
#pragma unroll
    for (int p = 0; p < 6; ++p) orow[ND + p * NC + j] = simv[p] * inv;
    if (j == 0) orow[ND + 96] = inv;

    const float inv6 = 1.0f / 6.0f;
#pragma unroll
    for (int r = 0; r < NC; ++r)
        out[(size_t)(b * NC + r) * OUTW + t] = neigh[r] * inv6;
}

extern "C" void kernel_launch(void* const* d_in, const int* in_sizes, int n_in,
                              void* d_out, int out_size, void* d_ws, size_t ws_size,
                              hipStream_t stream) {
    const float* e  = (const float*)d_in[0];
    const int* nmv  = (const int*)d_in[1];
    float* out      = (float*)d_out;
    float* nrm      = (float*)d_ws;   // 32768 floats = 128 KB

    norm_kernel<<<(NB * NC) / 4, 256, 0, stream>>>(e, nrm);
    graph_kernel<<<NB, 256, 0, stream>>>(e, nmv, nrm, out);
}

// Round 2
// 36.435 us; speedup vs baseline: 2.6764x; 2.6764x over previous
//
#include <hip/hip_runtime.h>

#define NB 2048
#define NC 16
#define ND 256
#define G  8
#define NT 14            // G + 6 tiles resident
#define TPB 512
#define OUTW 353         // ND + 96 + 1
#define THRED 0.8f

typedef short bf16x8 __attribute__((ext_vector_type(8)));
typedef unsigned short u16x8 __attribute__((ext_vector_type(8)));
typedef float f32x4 __attribute__((ext_vector_type(4)));

__device__ __forceinline__ unsigned short f2bf(float x) {   // RNE
    unsigned int u = __float_as_uint(x);
    u += 0x7FFFu + ((u >> 16) & 1u);
    return (unsigned short)(u >> 16);
}
__device__ __forceinline__ float bf2f(unsigned short h) {
    return __uint_as_float(((unsigned int)h) << 16);
}

// LDS tile: [tile][row(16)][256 bf16], byte-swizzle (row&7)<<4 (ushort idx <<3)
__global__ __launch_bounds__(TPB) void fused_kernel(const float* __restrict__ e,
                                                    const int* __restrict__ nm,
                                                    float* __restrict__ out) {
    __shared__ __align__(16) unsigned short T[NT * NC * ND];   // 112 KB
    __shared__ float norms[NT][NC];
    __shared__ float MskL[G][6][NC];

    const int t  = threadIdx.x;
    const int b0 = blockIdx.x * G;

    // ---------------- stage fp32 -> bf16 (swizzled), zero-fill OOB ----------------
#pragma unroll
    for (int q = 0; q < (NT * NC * ND / 4) / TPB; ++q) {       // 28 float4 each
        int idx  = q * TPB + t;
        int tile = idx >> 10, rem = idx & 1023;
        int row  = rem >> 6,  c4  = rem & 63;
        int gb   = b0 - 3 + tile;
        ushort4 v = make_ushort4(0, 0, 0, 0);
        if (gb >= 0 && gb < NB) {
            const float4 g = *reinterpret_cast<const float4*>(
                e + (size_t)(gb * NC + row) * ND + c4 * 4);
            v.x = f2bf(g.x); v.y = f2bf(g.y); v.z = f2bf(g.z); v.w = f2bf(g.w);
        }
        int sIdx = tile * 4096 + row * 256 + ((c4 * 4) ^ ((row & 7) << 3));
        *reinterpret_cast<ushort4*>(&T[sIdx]) = v;
    }

    // ---------------- masks (regs + LDS broadcast copy) ----------------
    const int w   = t >> 6, l = t & 63;
    const int col = l & 15, hi = l >> 4;
    const int b   = b0 + w;
    float nmv[6];
#pragma unroll
    for (int u = 0; u < 6; ++u) {              // u-3 = -3..2
        int gb = b + u - 3;
        nmv[u] = (gb >= 0 && gb < NB) ? (float)nm[gb * NC + col] : 0.f;
    }
    float maskv[6];
    maskv[0] = nmv[2];                         // left k=1: nm[b-1]
    maskv[1] = nmv[2] * nmv[1];
    maskv[2] = nmv[2] * nmv[1] * nmv[0];
    maskv[3] = nmv[3];                         // right k=1: nm[b]
    maskv[4] = nmv[3] * nmv[4];
    maskv[5] = nmv[3] * nmv[4] * nmv[5];
    if (l < 16) {
#pragma unroll
        for (int p = 0; p < 6; ++p) MskL[w][p][l] = maskv[p];
    }

    __syncthreads();

    // ---------------- per-row norms from staged bf16 ----------------
    if (t < NT * NC) {
        int tile = t >> 4, r = t & 15;
        float ssq = 0.f;
#pragma unroll 8
        for (int k8 = 0; k8 < 32; ++k8) {
            int sIdx = tile * 4096 + r * 256 + ((k8 * 8) ^ ((r & 7) << 3));
            u16x8 vv = *reinterpret_cast<u16x8*>(&T[sIdx]);
#pragma unroll
            for (int ee = 0; ee < 8; ++ee) { float f = bf2f(vv[ee]); ssq = fmaf(f, f, ssq); }
        }
        norms[tile][r] = sqrtf(ssq);
    }
    __syncthreads();

    const int offs[6] = {-1, -2, -3, 1, 2, 3};

    // ---------------- sims via MFMA: wave w owns b = b0+w ----------------
    bf16x8 af[8];
#pragma unroll
    for (int c = 0; c < 8; ++c) {
        int sIdx = (w + 3) * 4096 + col * 256 + (((c * 32) + hi * 8) ^ ((col & 7) << 3));
        af[c] = *reinterpret_cast<bf16x8*>(&T[sIdx]);
    }
    f32x4 acc[6];
#pragma unroll
    for (int p = 0; p < 6; ++p) {
        acc[p] = (f32x4){0.f, 0.f, 0.f, 0.f};
        const int tt = w + 3 + offs[p];
#pragma unroll
        for (int c = 0; c < 8; ++c) {
            int sIdx = tt * 4096 + col * 256 + (((c * 32) + hi * 8) ^ ((col & 7) << 3));
            bf16x8 bfr = *reinterpret_cast<bf16x8*>(&T[sIdx]);
            acc[p] = __builtin_amdgcn_mfma_f32_16x16x32_bf16(af[c], bfr, acc[p], 0, 0, 0);
        }
    }

    float na[4];
#pragma unroll
    for (int r4 = 0; r4 < 4; ++r4) na[r4] = norms[w + 3][hi * 4 + r4];

    float sim[6][4];
    float rowsum[4] = {0.f, 0.f, 0.f, 0.f};
#pragma unroll
    for (int p = 0; p < 6; ++p) {
        const int tt = w + 3 + offs[p];
        const float nbv = norms[tt][col];
        const bool mv = (maskv[p] != 0.f);
#pragma unroll
        for (int r4 = 0; r4 < 4; ++r4) {
            float qd = acc[p][r4] / fmaxf(na[r4] * nbv, 1e-8f);
            float s  = (mv && qd > THRED) ? fminf(qd, 1.f) : 0.f;
            sim[p][r4] = s;
            rowsum[r4] += s;
        }
    }
#pragma unroll
    for (int r4 = 0; r4 < 4; ++r4) {
#pragma unroll
        for (int o = 1; o < 16; o <<= 1) rowsum[r4] += __shfl_xor(rowsum[r4], o, 16);
    }

#pragma unroll
    for (int r4 = 0; r4 < 4; ++r4) {
        const float inv = 1.0f / fmaxf(rowsum[r4] + 1.0f, 1e-12f);
        size_t obase = (size_t)(b * NC + hi * 4 + r4) * OUTW;
#pragma unroll
        for (int p = 0; p < 6; ++p)
            out[obase + ND + p * NC + col] = sim[p][r4] * inv;
        if (col == 0) out[obase + ND + 96] = inv;
    }

    // ---------------- neighbor embedding (mean of 6 masked copies) ----------------
    const float s6 = 1.0f / 6.0f;
#pragma unroll 4
    for (int r = 0; r < NC; ++r) {
        float a0 = 0.f, a1 = 0.f, a2 = 0.f, a3 = 0.f;
#pragma unroll
        for (int p = 0; p < 6; ++p) {
            const int tt = w + 3 + offs[p];
            const float m = MskL[w][p][r];
            int sIdx = tt * 4096 + r * 256 + ((l * 4) ^ ((r & 7) << 3));
            ushort4 v = *reinterpret_cast<ushort4*>(&T[sIdx]);
            a0 = fmaf(m, bf2f(v.x), a0);
            a1 = fmaf(m, bf2f(v.y), a1);
            a2 = fmaf(m, bf2f(v.z), a2);
            a3 = fmaf(m, bf2f(v.w), a3);
        }
        size_t ob = (size_t)(b * NC + r) * OUTW + l * 4;
        out[ob + 0] = a0 * s6;
        out[ob + 1] = a1 * s6;
        out[ob + 2] = a2 * s6;
        out[ob + 3] = a3 * s6;
    }
}

extern "C" void kernel_launch(void* const* d_in, const int* in_sizes, int n_in,
                              void* d_out, int out_size, void* d_ws, size_t ws_size,
                              hipStream_t stream) {
    const float* e = (const float*)d_in[0];
    const int* nmv = (const int*)d_in[1];
    float* out     = (float*)d_out;
    fused_kernel<<<NB / G, TPB, 0, stream>>>(e, nmv, out);
}